// Round 9
// baseline (150.740 us; speedup 1.0000x reference)
//
#include <hip/hip_runtime.h>
#include <hip/hip_bf16.h>

// Problem constants (B=4, S=1024, d=512, H=8, hd=64)
#define BB 4
#define SS 1024
#define DD 512
#define HH 8
#define HD 64

typedef __attribute__((ext_vector_type(8))) short bf16x8;
typedef __attribute__((ext_vector_type(4))) float f32x4;

// fp32 -> bf16 round-to-nearest-even (finite inputs)
static __device__ __forceinline__ unsigned short f2b(float f) {
  union { float f; unsigned int u; } c; c.f = f;
  return (unsigned short)((c.u + 0x7fffu + ((c.u >> 16) & 1u)) >> 16);
}

// two fp32 -> packed bf16x2 (RNE, bit-identical to f2b pair) in ONE VALU op
static __device__ __forceinline__ unsigned cvtpk(float lo, float hi) {
  unsigned r;
  asm("v_cvt_pk_bf16_f32 %0, %1, %2" : "=v"(r) : "v"(lo), "v"(hi));
  return r;
}

// ---------------------------------------------------------------------------
// Fused prep (one dispatch, 3968 blocks):
//  [0,1024):    x fp32 -> bf16 (2M)
//  [1024,1280): in_proj_w q|k rows -> bf16 (512K)
//  [1280,1408): out_w -> bf16 (256K)
//  [1408,3456): mask bit-pack: 8 fp32 -> 1 byte
//  [3456,3968): V [B,S,H,hd] fp32 -> Vt [B,H,hd,S] bf16
// ---------------------------------------------------------------------------
__global__ __launch_bounds__(256) void prep(
    const float* __restrict__ x, const float* __restrict__ W1,
    const float* __restrict__ Wo, const float* __restrict__ Mmask,
    const float* __restrict__ V, unsigned short* __restrict__ xb,
    unsigned short* __restrict__ W1b, unsigned short* __restrict__ Wob,
    unsigned char* __restrict__ Mpack, unsigned short* __restrict__ Vt) {
  __shared__ float Ls[64][65];
  const int bid = blockIdx.x;
  const int tid = threadIdx.x;

  if (bid < 1408) {
    const float* src; unsigned short* dst; size_t off;
    if (bid < 1024) { src = x;  dst = xb;  off = ((size_t)bid * 256 + tid) * 8; }
    else if (bid < 1280) { src = W1; dst = W1b; off = ((size_t)(bid - 1024) * 256 + tid) * 8; }
    else { src = Wo; dst = Wob; off = ((size_t)(bid - 1280) * 256 + tid) * 8; }
    const float4 a = *(const float4*)(src + off);
    const float4 b = *(const float4*)(src + off + 4);
    union { unsigned short s[8]; uint4 v; } o;
    o.s[0] = f2b(a.x); o.s[1] = f2b(a.y); o.s[2] = f2b(a.z); o.s[3] = f2b(a.w);
    o.s[4] = f2b(b.x); o.s[5] = f2b(b.y); o.s[6] = f2b(b.z); o.s[7] = f2b(b.w);
    *(uint4*)(dst + off) = o.v;
  } else if (bid < 3456) {
    const size_t g = (size_t)(bid - 1408) * 256 + tid;
    const float4 a = *(const float4*)(Mmask + g * 8);
    const float4 b = *(const float4*)(Mmask + g * 8 + 4);
    unsigned v = 0;
    v |= (a.x > 0.5f) ? 1u : 0u;   v |= (a.y > 0.5f) ? 2u : 0u;
    v |= (a.z > 0.5f) ? 4u : 0u;   v |= (a.w > 0.5f) ? 8u : 0u;
    v |= (b.x > 0.5f) ? 16u : 0u;  v |= (b.y > 0.5f) ? 32u : 0u;
    v |= (b.z > 0.5f) ? 64u : 0u;  v |= (b.w > 0.5f) ? 128u : 0u;
    Mpack[g] = (unsigned char)v;
  } else {
    const int id = bid - 3456;
    const int s0 = (id & 15) * 64, h = (id >> 4) & 7, b = id >> 7;
    {
      const int r = tid >> 2, cs = (tid & 3) * 16;
      const float* src = V + ((size_t)((b * SS + s0 + r) * HH) + h) * HD + cs;
#pragma unroll
      for (int j = 0; j < 4; j++) {
        const float4 v = *(const float4*)(src + j * 4);
        Ls[r][cs + j * 4 + 0] = v.x; Ls[r][cs + j * 4 + 1] = v.y;
        Ls[r][cs + j * 4 + 2] = v.z; Ls[r][cs + j * 4 + 3] = v.w;
      }
    }
    __syncthreads();
    {
      const int d = tid >> 2, ss = (tid & 3) * 16;
      union { unsigned short s[16]; uint4 v[2]; } o;
#pragma unroll
      for (int j = 0; j < 16; j++) o.s[j] = f2b(Ls[ss + j][d]);
      unsigned short* dst =
          Vt + ((size_t)((b * HH + h) * HD + d)) * SS + s0 + ss;
      *(uint4*)dst = o.v[0];
      *(uint4*)(dst + 8) = o.v[1];
    }
  }
}

// ---------------------------------------------------------------------------
// GEMM1: qkb[4096,1024](bf16) = xb(bf16) @ W1b(bf16)^T + bias  (unchanged)
// ---------------------------------------------------------------------------
__global__ __launch_bounds__(256) void gemm_qk(
    const unsigned short* __restrict__ xb, const unsigned short* __restrict__ W1b,
    const float* __restrict__ bias, unsigned short* __restrict__ qkb) {
  __shared__ unsigned short As[128][40];
  __shared__ unsigned short Bs[64][40];
  const int tid = threadIdx.x;
  const int lane = tid & 63, wave = tid >> 6;
  const int l16 = lane & 15, quad = lane >> 4;
  const int row0 = blockIdx.y * 128, col0 = blockIdx.x * 64;

  f32x4 acc[2][4];
#pragma unroll
  for (int i = 0; i < 2; i++)
#pragma unroll
    for (int j = 0; j < 4; j++) acc[i][j] = (f32x4){0.f, 0.f, 0.f, 0.f};

  const int ra = tid >> 1, csa = (tid & 1) * 16;
  const int rb = tid >> 2, csb = (tid & 3) * 8;
  const unsigned short* ap = xb + (size_t)(row0 + ra) * DD + csa;
  const unsigned short* bp = W1b + (size_t)(col0 + rb) * DD + csb;

  uint4 pa0 = *(const uint4*)ap, pa1 = *(const uint4*)(ap + 8);
  uint4 pb = *(const uint4*)bp;

  for (int k0 = 0; k0 < DD; k0 += 32) {
    __syncthreads();
    *(uint4*)&As[ra][csa] = pa0;
    *(uint4*)&As[ra][csa + 8] = pa1;
    *(uint4*)&Bs[rb][csb] = pb;
    __syncthreads();
    if (k0 + 32 < DD) {  // prefetch next slab; vmcnt waits land next iter
      pa0 = *(const uint4*)(ap + k0 + 32);
      pa1 = *(const uint4*)(ap + k0 + 40);
      pb = *(const uint4*)(bp + k0 + 32);
    }

    const bf16x8 a0 = *(const bf16x8*)&As[wave * 32 + l16][quad * 8];
    const bf16x8 a1 = *(const bf16x8*)&As[wave * 32 + 16 + l16][quad * 8];
#pragma unroll
    for (int nt = 0; nt < 4; nt++) {
      const bf16x8 bb = *(const bf16x8*)&Bs[nt * 16 + l16][quad * 8];
      acc[0][nt] = __builtin_amdgcn_mfma_f32_16x16x32_bf16(a0, bb, acc[0][nt], 0, 0, 0);
      acc[1][nt] = __builtin_amdgcn_mfma_f32_16x16x32_bf16(a1, bb, acc[1][nt], 0, 0, 0);
    }
  }

#pragma unroll
  for (int nt = 0; nt < 4; nt++) {
    const int col = col0 + nt * 16 + l16;
    const float bv = bias[col];
    const float scale = (col < DD) ? 0.125f : 1.0f;
#pragma unroll
    for (int mi = 0; mi < 2; mi++)
#pragma unroll
      for (int reg = 0; reg < 4; reg++) {
        const int row = row0 + wave * 32 + mi * 16 + quad * 4 + reg;
        qkb[(size_t)row * 1024 + col] = f2b((acc[mi][nt][reg] + bv) * scale);
      }
  }
}

// ---------------------------------------------------------------------------
// GEMM3: out[4096,512](fp32) = attnb(bf16) @ Wob(bf16)^T + out_b  (unchanged)
// ---------------------------------------------------------------------------
__global__ __launch_bounds__(256) void gemm_out(
    const unsigned short* __restrict__ Ab, const unsigned short* __restrict__ Wob,
    const float* __restrict__ bias, float* __restrict__ out) {
  __shared__ unsigned short As[64][40];
  __shared__ unsigned short Bs[64][40];
  const int tid = threadIdx.x;
  const int lane = tid & 63, wave = tid >> 6;
  const int l16 = lane & 15, quad = lane >> 4;
  const int row0 = blockIdx.y * 64, col0 = blockIdx.x * 64;

  f32x4 acc[4];
#pragma unroll
  for (int j = 0; j < 4; j++) acc[j] = (f32x4){0.f, 0.f, 0.f, 0.f};

  const int r = tid >> 2, cs = (tid & 3) * 8;
  const unsigned short* ap = Ab + (size_t)(row0 + r) * DD + cs;
  const unsigned short* bp = Wob + (size_t)(col0 + r) * DD + cs;

  uint4 pa = *(const uint4*)ap;
  uint4 pb = *(const uint4*)bp;

  for (int k0 = 0; k0 < DD; k0 += 32) {
    __syncthreads();
    *(uint4*)&As[r][cs] = pa;
    *(uint4*)&Bs[r][cs] = pb;
    __syncthreads();
    if (k0 + 32 < DD) {
      pa = *(const uint4*)(ap + k0 + 32);
      pb = *(const uint4*)(bp + k0 + 32);
    }

    const bf16x8 a0 = *(const bf16x8*)&As[wave * 16 + l16][quad * 8];
#pragma unroll
    for (int nt = 0; nt < 4; nt++) {
      const bf16x8 bb = *(const bf16x8*)&Bs[nt * 16 + l16][quad * 8];
      acc[nt] = __builtin_amdgcn_mfma_f32_16x16x32_bf16(a0, bb, acc[nt], 0, 0, 0);
    }
  }

#pragma unroll
  for (int nt = 0; nt < 4; nt++) {
    const int col = col0 + nt * 16 + l16;
    const float bv = bias[col];
#pragma unroll
    for (int reg = 0; reg < 4; reg++) {
      const int row = row0 + wave * 16 + quad * 4 + reg;
      out[(size_t)row * DD + col] = acc[nt][reg] + bv;
    }
  }
}

// ---------------------------------------------------------------------------
// Fused split-k flash attention (r15): single-barrier pipeline.
// Changes vs r14 (which had 2 barriers/iter around combined K+V staging):
//  - V fragments read DIRECTLY from global Vt (layout [d][s] == B-frag
//    layout, contiguous 16B). V is L2-local via the XCD swizzle; the 8
//    loads/wave/iter issue early and hide under QK^T+softmax. Vs LDS gone.
//  - K double-buffered in LDS: stage Ks[nxt] DURING compute of Ks[cur];
//    ONE __syncthreads() per iteration (8 barriers instead of 16).
//  - Everything else identical to r14 (same MFMA order -> absmax must stay
//    0.0004882812): cvt_pk P pack, wave-private P rows, XCD-aware decode,
//    in-block split-k epilogue through LDS.
// LDS: QP 9.2K + P2 9.2K + Ks[2][2][64][72] 36.9K + SmS 0.5K = 55.8KB
//   -> 2 blocks/CU (16 waves/CU), unchanged occupancy.
// ---------------------------------------------------------------------------
__global__ __launch_bounds__(512, 4) void flash_attn_fused(
    const unsigned short* __restrict__ qkb, const unsigned short* __restrict__ Vt,
    const unsigned char* __restrict__ Mpack, unsigned short* __restrict__ attnb) {
  __shared__ unsigned short QP[64][72];        // Q staging; then P for sp=0
  __shared__ unsigned short P2[64][72];        // P for sp=1 waves
  __shared__ unsigned short Ks[2][2][64][72];  // [buf][kh][s][k]; epilogue O
  __shared__ float SmS[2][64];                 // per-half row denominators

  const int tid = threadIdx.x;
  const int lane = tid & 63, wave = tid >> 6;
  const int l16 = lane & 15, quad = lane >> 4;
  const int wq = wave & 3, sp = wave >> 2;

  // XCD-aware decode: g%8 selects the XCD (round-robin dispatch); keep all
  // 16 q-tiles of a (b,h) group on one XCD. Bijective for 512 blocks.
  const int g = blockIdx.x;
  const int xcd = g & 7, loc = g >> 3;       // loc in [0,64)
  const int gr = xcd + 8 * (loc >> 4);       // (b,h) group in [0,32)
  const int q0 = (loc & 15) * 64;
  const int h = gr & 7;
  const int b = gr >> 3;

  const int r2 = tid >> 3, cs2 = (tid & 7) * 8;  // 512-thread staging

  {  // stage Q tile (all 64 rows; frags read into regs before P aliases it)
    const unsigned short* s = qkb + (size_t)(b * SS + q0 + r2) * 1024 + h * HD + cs2;
    *(uint4*)&QP[r2][cs2] = *(const uint4*)s;
  }

  // mask word pipeline: q = q0 + wq*16 + l16, this half's 8 k-tiles
  const unsigned char* mp =
      Mpack + (size_t)(b * SS + q0 + wq * 16 + l16) * 128 + sp * 64;
  uint2 pm = *(const uint2*)mp;

  // per-thread K staging pointers (both halves staged by all threads)
  const unsigned short* kp0 =
      qkb + (size_t)(b * SS + r2) * 1024 + DD + h * HD + cs2;   // keys [0,512)
  const unsigned short* kp1 = kp0 + (size_t)512 * 1024;         // keys [512,1024)

  // V base for this wave's direct B-frag loads: d = dt*16+l16, s-offset
  const unsigned short* vb =
      Vt + ((size_t)((b * HH + h) * HD + l16)) * SS + sp * 512 + quad * 8;

  // tile 0 -> Ks[0] (before the Q barrier), then prefetch tile 1 into regs
  {
    const uint4 t0k0 = *(const uint4*)kp0;
    const uint4 t0k1 = *(const uint4*)kp1;
    *(uint4*)&Ks[0][0][r2][cs2] = t0k0;
    *(uint4*)&Ks[0][1][r2][cs2] = t0k1;
  }
  uint4 pk0 = *(const uint4*)(kp0 + (size_t)64 * 1024);
  uint4 pk1 = *(const uint4*)(kp1 + (size_t)64 * 1024);

  __syncthreads();  // Q staging + Ks[0] visible
  const bf16x8 bQ0 = *(const bf16x8*)&QP[wq * 16 + l16][quad * 8];
  const bf16x8 bQ1 = *(const bf16x8*)&QP[wq * 16 + l16][32 + quad * 8];
  unsigned short(*Ps)[72] =
      (unsigned short(*)[72])(sp ? &P2[wq * 16][0] : &QP[wq * 16][0]);

  float Smp = 0.f;
  f32x4 O[4];
#pragma unroll
  for (int i = 0; i < 4; i++) O[i] = (f32x4){0.f, 0.f, 0.f, 0.f};

#pragma unroll
  for (int i = 0; i < 8; i++) {
    const int cur = i & 1, nxt = cur ^ 1;
    const uint2 pm_cur = pm;

    if (i < 7) {  // stage tile i+1 into the other buffer (no reader this iter)
      *(uint4*)&Ks[nxt][0][r2][cs2] = pk0;
      *(uint4*)&Ks[nxt][1][r2][cs2] = pk1;
      if (i < 6) {  // prefetch tile i+2; latency hidden by compute below
        pk0 = *(const uint4*)(kp0 + (size_t)(i + 2) * 64 * 1024);
        pk1 = *(const uint4*)(kp1 + (size_t)(i + 2) * 64 * 1024);
      }
      pm = *(const uint2*)(mp + (i + 1) * 8);
    }

    // ---- S^T tiles: D[s=quad*4+reg][q=l16]; exp, mask-bit select, P pack ----
#pragma unroll
    for (int t = 0; t < 4; t++) {
      const bf16x8 aK0 = *(const bf16x8*)&Ks[cur][sp][t * 16 + l16][quad * 8];
      const bf16x8 aK1 = *(const bf16x8*)&Ks[cur][sp][t * 16 + l16][32 + quad * 8];
      f32x4 a = (f32x4){0.f, 0.f, 0.f, 0.f};
      a = __builtin_amdgcn_mfma_f32_16x16x32_bf16(aK0, bQ0, a, 0, 0, 0);
      a = __builtin_amdgcn_mfma_f32_16x16x32_bf16(aK1, bQ1, a, 0, 0, 0);
      const unsigned nib =
          ((t < 2 ? pm_cur.x : pm_cur.y) >> ((t & 1) * 16 + quad * 4)) & 0xFu;
      float e0 = __expf(a[0]); e0 = (nib & 1u) ? e0 : 0.f;
      float e1 = __expf(a[1]); e1 = (nib & 2u) ? e1 : 0.f;
      float e2 = __expf(a[2]); e2 = (nib & 4u) ? e2 : 0.f;
      float e3 = __expf(a[3]); e3 = (nib & 8u) ? e3 : 0.f;
      Smp += (e0 + e1) + (e2 + e3);
      uint2 w;
      w.x = cvtpk(e0, e1);   // v_cvt_pk_bf16_f32: 2 f32 -> bf16x2, RNE
      w.y = cvtpk(e2, e3);
      *(uint2*)&Ps[l16][t * 16 + quad * 4] = w;  // ds_write_b64, wave-private
    }

    // ---- O += P @ V (P via wave-private LDS; V DIRECT from L2-local Vt) ----
    const bf16x8 aP0 = *(const bf16x8*)&Ps[l16][quad * 8];
    const bf16x8 aP1 = *(const bf16x8*)&Ps[l16][32 + quad * 8];
#pragma unroll
    for (int dt = 0; dt < 4; dt++) {
      const unsigned short* vt = vb + (size_t)(dt * 16) * SS + i * 64;
      const bf16x8 bV0 = *(const bf16x8*)vt;
      const bf16x8 bV1 = *(const bf16x8*)(vt + 32);
      O[dt] = __builtin_amdgcn_mfma_f32_16x16x32_bf16(aP0, bV0, O[dt], 0, 0, 0);
      O[dt] = __builtin_amdgcn_mfma_f32_16x16x32_bf16(aP1, bV1, O[dt], 0, 0, 0);
    }

    __syncthreads();  // Ks[nxt] visible; Ks[cur] reads drained for reuse
  }

  // ---- epilogue: in-block split-k combine through LDS ----
  Smp += __shfl_xor(Smp, 16);
  Smp += __shfl_xor(Smp, 32);
  if (lane < 16) SmS[sp][wq * 16 + lane] = Smp;

  __syncthreads();  // SmS visible (loop's last barrier drained Ks reads)
  float* Of = reinterpret_cast<float*>(&Ks[0][0][0][0]);  // 16 KB <= 18.4 KB
  if (sp == 1) {
#pragma unroll
    for (int dt = 0; dt < 4; dt++)
#pragma unroll
      for (int reg = 0; reg < 4; reg++)
        Of[(wq * 16 + quad * 4 + reg) * 64 + dt * 16 + l16] = O[dt][reg];
  }
  __syncthreads();

  if (sp == 0) {
    float inv[4];
#pragma unroll
    for (int reg = 0; reg < 4; reg++) {
      const int ql = wq * 16 + quad * 4 + reg;
      inv[reg] = 1.0f / (SmS[0][ql] + SmS[1][ql] + 1e-12f);
    }
#pragma unroll
    for (int dt = 0; dt < 4; dt++)
#pragma unroll
      for (int reg = 0; reg < 4; reg++) {
        const int ql = wq * 16 + quad * 4 + reg;
        const float v = (O[dt][reg] + Of[ql * 64 + dt * 16 + l16]) * inv[reg];
        attnb[(size_t)(b * SS + q0 + ql) * DD + h * HD + dt * 16 + l16] = f2b(v);
      }
  }
}

// ---------------------------------------------------------------------------
extern "C" void kernel_launch(void* const* d_in, const int* in_sizes, int n_in,
                              void* d_out, int out_size, void* d_ws,
                              size_t ws_size, hipStream_t stream) {
  const float* x = (const float*)d_in[0];          // [4,1024,512]
  const float* V = (const float*)d_in[1];          // [4,1024,8,64]
  const float* Mmask = (const float*)d_in[2];      // [4,1024,1024]
  const float* in_proj_w = (const float*)d_in[3];  // [1536,512]
  const float* in_proj_b = (const float*)d_in[4];  // [1536]
  const float* out_w = (const float*)d_in[5];      // [512,512]
  const float* out_b = (const float*)d_in[6];      // [512]
  float* out = (float*)d_out;                      // [4,1024,512]

  unsigned char* ws = (unsigned char*)d_ws;
  unsigned short* qkb   = (unsigned short*)(ws);                     // 8 MB
  unsigned short* xb    = (unsigned short*)(ws + (8ull << 20));      // 4 MB
  unsigned short* W1b   = (unsigned short*)(ws + (12ull << 20));     // 1 MB
  unsigned short* Wob   = (unsigned short*)(ws + (13ull << 20));     // 0.5 MB
  unsigned short* Vt    = (unsigned short*)(ws + (14ull << 20));     // 4 MB
  unsigned short* attnb = (unsigned short*)(ws + (18ull << 20));     // 4 MB
  unsigned char*  Mpack = ws + (38ull << 20) + (256u << 10);         // 512 KB

  prep<<<3968, 256, 0, stream>>>(x, in_proj_w, out_w, Mmask, V,
                                 xb, W1b, Wob, Mpack, Vt);
  gemm_qk<<<dim3(16, 32), 256, 0, stream>>>(xb, W1b, in_proj_b, qkb);
  flash_attn_fused<<<512, 512, 0, stream>>>(qkb, Vt, Mpack, attnb);
  gemm_out<<<dim3(8, 64), 256, 0, stream>>>(attnb, Wob, out_b, out);
}

// Round 10
// 131.995 us; speedup vs baseline: 1.1420x; 1.1420x over previous
//
#include <hip/hip_runtime.h>
#include <hip/hip_bf16.h>

// Problem constants (B=4, S=1024, d=512, H=8, hd=64)
#define BB 4
#define SS 1024
#define DD 512
#define HH 8
#define HD 64

typedef __attribute__((ext_vector_type(8))) short bf16x8;
typedef __attribute__((ext_vector_type(4))) float f32x4;

// fp32 -> bf16 round-to-nearest-even (finite inputs)
static __device__ __forceinline__ unsigned short f2b(float f) {
  union { float f; unsigned int u; } c; c.f = f;
  return (unsigned short)((c.u + 0x7fffu + ((c.u >> 16) & 1u)) >> 16);
}

// two fp32 -> packed bf16x2 (RNE, bit-identical to f2b pair) in ONE VALU op
static __device__ __forceinline__ unsigned cvtpk(float lo, float hi) {
  unsigned r;
  asm("v_cvt_pk_bf16_f32 %0, %1, %2" : "=v"(r) : "v"(lo), "v"(hi));
  return r;
}

// ---------------------------------------------------------------------------
// Fused prep (one dispatch, 3968 blocks):
//  [0,1024):    x fp32 -> bf16 (2M)
//  [1024,1280): in_proj_w q|k rows -> bf16 (512K)
//  [1280,1408): out_w -> bf16 (256K)
//  [1408,3456): mask bit-pack: 8 fp32 -> 1 byte
//  [3456,3968): V [B,S,H,hd] fp32 -> Vt [B,H,hd,S] bf16
// ---------------------------------------------------------------------------
__global__ __launch_bounds__(256) void prep(
    const float* __restrict__ x, const float* __restrict__ W1,
    const float* __restrict__ Wo, const float* __restrict__ Mmask,
    const float* __restrict__ V, unsigned short* __restrict__ xb,
    unsigned short* __restrict__ W1b, unsigned short* __restrict__ Wob,
    unsigned char* __restrict__ Mpack, unsigned short* __restrict__ Vt) {
  __shared__ float Ls[64][65];
  const int bid = blockIdx.x;
  const int tid = threadIdx.x;

  if (bid < 1408) {
    const float* src; unsigned short* dst; size_t off;
    if (bid < 1024) { src = x;  dst = xb;  off = ((size_t)bid * 256 + tid) * 8; }
    else if (bid < 1280) { src = W1; dst = W1b; off = ((size_t)(bid - 1024) * 256 + tid) * 8; }
    else { src = Wo; dst = Wob; off = ((size_t)(bid - 1280) * 256 + tid) * 8; }
    const float4 a = *(const float4*)(src + off);
    const float4 b = *(const float4*)(src + off + 4);
    union { unsigned short s[8]; uint4 v; } o;
    o.s[0] = f2b(a.x); o.s[1] = f2b(a.y); o.s[2] = f2b(a.z); o.s[3] = f2b(a.w);
    o.s[4] = f2b(b.x); o.s[5] = f2b(b.y); o.s[6] = f2b(b.z); o.s[7] = f2b(b.w);
    *(uint4*)(dst + off) = o.v;
  } else if (bid < 3456) {
    const size_t g = (size_t)(bid - 1408) * 256 + tid;
    const float4 a = *(const float4*)(Mmask + g * 8);
    const float4 b = *(const float4*)(Mmask + g * 8 + 4);
    unsigned v = 0;
    v |= (a.x > 0.5f) ? 1u : 0u;   v |= (a.y > 0.5f) ? 2u : 0u;
    v |= (a.z > 0.5f) ? 4u : 0u;   v |= (a.w > 0.5f) ? 8u : 0u;
    v |= (b.x > 0.5f) ? 16u : 0u;  v |= (b.y > 0.5f) ? 32u : 0u;
    v |= (b.z > 0.5f) ? 64u : 0u;  v |= (b.w > 0.5f) ? 128u : 0u;
    Mpack[g] = (unsigned char)v;
  } else {
    const int id = bid - 3456;
    const int s0 = (id & 15) * 64, h = (id >> 4) & 7, b = id >> 7;
    {
      const int r = tid >> 2, cs = (tid & 3) * 16;
      const float* src = V + ((size_t)((b * SS + s0 + r) * HH) + h) * HD + cs;
#pragma unroll
      for (int j = 0; j < 4; j++) {
        const float4 v = *(const float4*)(src + j * 4);
        Ls[r][cs + j * 4 + 0] = v.x; Ls[r][cs + j * 4 + 1] = v.y;
        Ls[r][cs + j * 4 + 2] = v.z; Ls[r][cs + j * 4 + 3] = v.w;
      }
    }
    __syncthreads();
    {
      const int d = tid >> 2, ss = (tid & 3) * 16;
      union { unsigned short s[16]; uint4 v[2]; } o;
#pragma unroll
      for (int j = 0; j < 16; j++) o.s[j] = f2b(Ls[ss + j][d]);
      unsigned short* dst =
          Vt + ((size_t)((b * HH + h) * HD + d)) * SS + s0 + ss;
      *(uint4*)dst = o.v[0];
      *(uint4*)(dst + 8) = o.v[1];
    }
  }
}

// ---------------------------------------------------------------------------
// GEMM1: qkb[4096,1024](bf16) = xb(bf16) @ W1b(bf16)^T + bias  (unchanged)
// ---------------------------------------------------------------------------
__global__ __launch_bounds__(256) void gemm_qk(
    const unsigned short* __restrict__ xb, const unsigned short* __restrict__ W1b,
    const float* __restrict__ bias, unsigned short* __restrict__ qkb) {
  __shared__ unsigned short As[128][40];
  __shared__ unsigned short Bs[64][40];
  const int tid = threadIdx.x;
  const int lane = tid & 63, wave = tid >> 6;
  const int l16 = lane & 15, quad = lane >> 4;
  const int row0 = blockIdx.y * 128, col0 = blockIdx.x * 64;

  f32x4 acc[2][4];
#pragma unroll
  for (int i = 0; i < 2; i++)
#pragma unroll
    for (int j = 0; j < 4; j++) acc[i][j] = (f32x4){0.f, 0.f, 0.f, 0.f};

  const int ra = tid >> 1, csa = (tid & 1) * 16;
  const int rb = tid >> 2, csb = (tid & 3) * 8;
  const unsigned short* ap = xb + (size_t)(row0 + ra) * DD + csa;
  const unsigned short* bp = W1b + (size_t)(col0 + rb) * DD + csb;

  uint4 pa0 = *(const uint4*)ap, pa1 = *(const uint4*)(ap + 8);
  uint4 pb = *(const uint4*)bp;

  for (int k0 = 0; k0 < DD; k0 += 32) {
    __syncthreads();
    *(uint4*)&As[ra][csa] = pa0;
    *(uint4*)&As[ra][csa + 8] = pa1;
    *(uint4*)&Bs[rb][csb] = pb;
    __syncthreads();
    if (k0 + 32 < DD) {  // prefetch next slab; vmcnt waits land next iter
      pa0 = *(const uint4*)(ap + k0 + 32);
      pa1 = *(const uint4*)(ap + k0 + 40);
      pb = *(const uint4*)(bp + k0 + 32);
    }

    const bf16x8 a0 = *(const bf16x8*)&As[wave * 32 + l16][quad * 8];
    const bf16x8 a1 = *(const bf16x8*)&As[wave * 32 + 16 + l16][quad * 8];
#pragma unroll
    for (int nt = 0; nt < 4; nt++) {
      const bf16x8 bb = *(const bf16x8*)&Bs[nt * 16 + l16][quad * 8];
      acc[0][nt] = __builtin_amdgcn_mfma_f32_16x16x32_bf16(a0, bb, acc[0][nt], 0, 0, 0);
      acc[1][nt] = __builtin_amdgcn_mfma_f32_16x16x32_bf16(a1, bb, acc[1][nt], 0, 0, 0);
    }
  }

#pragma unroll
  for (int nt = 0; nt < 4; nt++) {
    const int col = col0 + nt * 16 + l16;
    const float bv = bias[col];
    const float scale = (col < DD) ? 0.125f : 1.0f;
#pragma unroll
    for (int mi = 0; mi < 2; mi++)
#pragma unroll
      for (int reg = 0; reg < 4; reg++) {
        const int row = row0 + wave * 32 + mi * 16 + quad * 4 + reg;
        qkb[(size_t)row * 1024 + col] = f2b((acc[mi][nt][reg] + bv) * scale);
      }
  }
}

// ---------------------------------------------------------------------------
// GEMM3: out[4096,512](fp32) = attnb(bf16) @ Wob(bf16)^T + out_b  (unchanged)
// ---------------------------------------------------------------------------
__global__ __launch_bounds__(256) void gemm_out(
    const unsigned short* __restrict__ Ab, const unsigned short* __restrict__ Wob,
    const float* __restrict__ bias, float* __restrict__ out) {
  __shared__ unsigned short As[64][40];
  __shared__ unsigned short Bs[64][40];
  const int tid = threadIdx.x;
  const int lane = tid & 63, wave = tid >> 6;
  const int l16 = lane & 15, quad = lane >> 4;
  const int row0 = blockIdx.y * 64, col0 = blockIdx.x * 64;

  f32x4 acc[4];
#pragma unroll
  for (int j = 0; j < 4; j++) acc[j] = (f32x4){0.f, 0.f, 0.f, 0.f};

  const int r = tid >> 2, cs = (tid & 3) * 8;
  const unsigned short* ap = Ab + (size_t)(row0 + r) * DD + cs;
  const unsigned short* bp = Wob + (size_t)(col0 + r) * DD + cs;

  uint4 pa = *(const uint4*)ap;
  uint4 pb = *(const uint4*)bp;

  for (int k0 = 0; k0 < DD; k0 += 32) {
    __syncthreads();
    *(uint4*)&As[r][cs] = pa;
    *(uint4*)&Bs[r][cs] = pb;
    __syncthreads();
    if (k0 + 32 < DD) {
      pa = *(const uint4*)(ap + k0 + 32);
      pb = *(const uint4*)(bp + k0 + 32);
    }

    const bf16x8 a0 = *(const bf16x8*)&As[wave * 16 + l16][quad * 8];
#pragma unroll
    for (int nt = 0; nt < 4; nt++) {
      const bf16x8 bb = *(const bf16x8*)&Bs[nt * 16 + l16][quad * 8];
      acc[nt] = __builtin_amdgcn_mfma_f32_16x16x32_bf16(a0, bb, acc[nt], 0, 0, 0);
    }
  }

#pragma unroll
  for (int nt = 0; nt < 4; nt++) {
    const int col = col0 + nt * 16 + l16;
    const float bv = bias[col];
#pragma unroll
    for (int reg = 0; reg < 4; reg++) {
      const int row = row0 + wave * 16 + quad * 4 + reg;
      out[(size_t)row * DD + col] = acc[nt][reg] + bv;
    }
  }
}

// ---------------------------------------------------------------------------
// Fused split-k flash attention (r16): r14 kernel (best verified: 130.4us)
// + s_setprio(1) around the MFMA clusters (T5). Mechanism: 16 waves/CU in
// 2 independent blocks drift to different phases; raising priority while
// issuing MFMA keeps the matrix pipe fed when co-resident waves are doing
// staging/softmax. Runtime hint only -> absmax must stay 0.0004882812.
// r15's lesson (V-direct + single barrier regressed 23->43us) confirmed
// LDS staging of BOTH K and V is load-bearing; reverted.
//  - 512 thr / 8 waves; waves 0-3 = k-tiles [0,8), waves 4-7 = [8,16).
//  - K/V both halves staged per iter (register-prefetch, 2 barriers).
//  - P in wave-private LDS rows (QP aliased for sp=0, P2 for sp=1).
//  - cvt_pk P pack; XCD-aware flat grid decode (16 q-tiles of a (b,h)
//    group on one XCD); in-block split-k epilogue through LDS.
// ---------------------------------------------------------------------------
__global__ __launch_bounds__(512, 4) void flash_attn_fused(
    const unsigned short* __restrict__ qkb, const unsigned short* __restrict__ Vt,
    const unsigned char* __restrict__ Mpack, unsigned short* __restrict__ attnb) {
  __shared__ unsigned short QP[64][72];     // Q staging; then P for sp=0 waves
  __shared__ unsigned short P2[64][72];     // P for sp=1 waves
  __shared__ unsigned short Ks[2][64][72];  // K tiles, both halves; epilogue O
  __shared__ unsigned short Vs[2][64][72];  // [d][s], both halves
  __shared__ float SmS[2][64];              // per-half row denominators

  const int tid = threadIdx.x;
  const int lane = tid & 63, wave = tid >> 6;
  const int l16 = lane & 15, quad = lane >> 4;
  const int wq = wave & 3, sp = wave >> 2;

  // XCD-aware decode: g%8 selects the XCD (round-robin dispatch); keep all
  // 16 q-tiles of a (b,h) group on one XCD. Bijective for 512 blocks.
  const int g = blockIdx.x;
  const int xcd = g & 7, loc = g >> 3;       // loc in [0,64)
  const int gr = xcd + 8 * (loc >> 4);       // (b,h) group in [0,32)
  const int q0 = (loc & 15) * 64;
  const int h = gr & 7;
  const int b = gr >> 3;

  const int r2 = tid >> 3, cs2 = (tid & 7) * 8;  // 512-thread staging

  {  // stage Q tile (all 64 rows; frags read into regs before P aliases it)
    const unsigned short* s = qkb + (size_t)(b * SS + q0 + r2) * 1024 + h * HD + cs2;
    *(uint4*)&QP[r2][cs2] = *(const uint4*)s;
  }

  // mask word pipeline: q = q0 + wq*16 + l16, this half's 8 k-tiles
  const unsigned char* mp =
      Mpack + (size_t)(b * SS + q0 + wq * 16 + l16) * 128 + sp * 64;
  uint2 pm = *(const uint2*)mp;

  __syncthreads();
  const bf16x8 bQ0 = *(const bf16x8*)&QP[wq * 16 + l16][quad * 8];
  const bf16x8 bQ1 = *(const bf16x8*)&QP[wq * 16 + l16][32 + quad * 8];
  unsigned short(*Ps)[72] =
      (unsigned short(*)[72])(sp ? &P2[wq * 16][0] : &QP[wq * 16][0]);

  float Smp = 0.f;
  f32x4 O[4];
#pragma unroll
  for (int i = 0; i < 4; i++) O[i] = (f32x4){0.f, 0.f, 0.f, 0.f};

  // per-thread staging pointers: each thread stages 16 B of K and V per half
  const unsigned short* kp0 =
      qkb + (size_t)(b * SS + r2) * 1024 + DD + h * HD + cs2;          // keys [0,512)
  const unsigned short* kp1 = kp0 + (size_t)512 * 1024;                 // keys [512,1024)
  const unsigned short* vp0 =
      Vt + ((size_t)((b * HH + h) * HD + r2)) * SS + cs2;
  const unsigned short* vp1 = vp0 + 512;

  uint4 pk0 = *(const uint4*)kp0, pk1 = *(const uint4*)kp1;
  uint4 pv0 = *(const uint4*)vp0, pv1 = *(const uint4*)vp1;

#pragma unroll
  for (int i = 0; i < 8; i++) {
    __syncthreads();  // prior iter's Ks/Vs frag reads complete
    *(uint4*)&Ks[0][r2][cs2] = pk0;
    *(uint4*)&Ks[1][r2][cs2] = pk1;
    *(uint4*)&Vs[0][r2][cs2] = pv0;
    *(uint4*)&Vs[1][r2][cs2] = pv1;
    __syncthreads();

    const uint2 pm_cur = pm;
    if (i < 7) {  // prefetch tile i+1; latency hidden by compute below
      pk0 = *(const uint4*)(kp0 + (size_t)(i + 1) * 64 * 1024);
      pk1 = *(const uint4*)(kp1 + (size_t)(i + 1) * 64 * 1024);
      pv0 = *(const uint4*)(vp0 + (i + 1) * 64);
      pv1 = *(const uint4*)(vp1 + (i + 1) * 64);
      pm = *(const uint2*)(mp + (i + 1) * 8);
    }

    // ---- S^T tiles: D[s=quad*4+reg][q=l16]; exp, mask-bit select, P pack ----
#pragma unroll
    for (int t = 0; t < 4; t++) {
      const bf16x8 aK0 = *(const bf16x8*)&Ks[sp][t * 16 + l16][quad * 8];
      const bf16x8 aK1 = *(const bf16x8*)&Ks[sp][t * 16 + l16][32 + quad * 8];
      f32x4 a = (f32x4){0.f, 0.f, 0.f, 0.f};
      __builtin_amdgcn_s_setprio(1);
      a = __builtin_amdgcn_mfma_f32_16x16x32_bf16(aK0, bQ0, a, 0, 0, 0);
      a = __builtin_amdgcn_mfma_f32_16x16x32_bf16(aK1, bQ1, a, 0, 0, 0);
      __builtin_amdgcn_s_setprio(0);
      const unsigned nib =
          ((t < 2 ? pm_cur.x : pm_cur.y) >> ((t & 1) * 16 + quad * 4)) & 0xFu;
      float e0 = __expf(a[0]); e0 = (nib & 1u) ? e0 : 0.f;
      float e1 = __expf(a[1]); e1 = (nib & 2u) ? e1 : 0.f;
      float e2 = __expf(a[2]); e2 = (nib & 4u) ? e2 : 0.f;
      float e3 = __expf(a[3]); e3 = (nib & 8u) ? e3 : 0.f;
      Smp += (e0 + e1) + (e2 + e3);
      uint2 w;
      w.x = cvtpk(e0, e1);   // v_cvt_pk_bf16_f32: 2 f32 -> bf16x2, RNE
      w.y = cvtpk(e2, e3);
      *(uint2*)&Ps[l16][t * 16 + quad * 4] = w;  // ds_write_b64, wave-private
    }

    // ---- O += P @ V (wave-private P; in-wave DS ordering suffices) ----
    const bf16x8 aP0 = *(const bf16x8*)&Ps[l16][quad * 8];
    const bf16x8 aP1 = *(const bf16x8*)&Ps[l16][32 + quad * 8];
    __builtin_amdgcn_s_setprio(1);
#pragma unroll
    for (int dt = 0; dt < 4; dt++) {
      const bf16x8 bV0 = *(const bf16x8*)&Vs[sp][dt * 16 + l16][quad * 8];
      const bf16x8 bV1 = *(const bf16x8*)&Vs[sp][dt * 16 + l16][32 + quad * 8];
      O[dt] = __builtin_amdgcn_mfma_f32_16x16x32_bf16(aP0, bV0, O[dt], 0, 0, 0);
      O[dt] = __builtin_amdgcn_mfma_f32_16x16x32_bf16(aP1, bV1, O[dt], 0, 0, 0);
    }
    __builtin_amdgcn_s_setprio(0);
  }

  // ---- epilogue: in-block split-k combine through LDS ----
  Smp += __shfl_xor(Smp, 16);
  Smp += __shfl_xor(Smp, 32);
  if (lane < 16) SmS[sp][wq * 16 + lane] = Smp;

  __syncthreads();  // all Ks reads drained; SmS visible
  float* Of = reinterpret_cast<float*>(&Ks[0][0][0]);  // 16 KB <= sizeof(Ks)
  if (sp == 1) {
#pragma unroll
    for (int dt = 0; dt < 4; dt++)
#pragma unroll
      for (int reg = 0; reg < 4; reg++)
        Of[(wq * 16 + quad * 4 + reg) * 64 + dt * 16 + l16] = O[dt][reg];
  }
  __syncthreads();

  if (sp == 0) {
    float inv[4];
#pragma unroll
    for (int reg = 0; reg < 4; reg++) {
      const int ql = wq * 16 + quad * 4 + reg;
      inv[reg] = 1.0f / (SmS[0][ql] + SmS[1][ql] + 1e-12f);
    }
#pragma unroll
    for (int dt = 0; dt < 4; dt++)
#pragma unroll
      for (int reg = 0; reg < 4; reg++) {
        const int ql = wq * 16 + quad * 4 + reg;
        const float v = (O[dt][reg] + Of[ql * 64 + dt * 16 + l16]) * inv[reg];
        attnb[(size_t)(b * SS + q0 + ql) * DD + h * HD + dt * 16 + l16] = f2b(v);
      }
  }
}

// ---------------------------------------------------------------------------
extern "C" void kernel_launch(void* const* d_in, const int* in_sizes, int n_in,
                              void* d_out, int out_size, void* d_ws,
                              size_t ws_size, hipStream_t stream) {
  const float* x = (const float*)d_in[0];          // [4,1024,512]
  const float* V = (const float*)d_in[1];          // [4,1024,8,64]
  const float* Mmask = (const float*)d_in[2];      // [4,1024,1024]
  const float* in_proj_w = (const float*)d_in[3];  // [1536,512]
  const float* in_proj_b = (const float*)d_in[4];  // [1536]
  const float* out_w = (const float*)d_in[5];      // [512,512]
  const float* out_b = (const float*)d_in[6];      // [512]
  float* out = (float*)d_out;                      // [4,1024,512]

  unsigned char* ws = (unsigned char*)d_ws;
  unsigned short* qkb   = (unsigned short*)(ws);                     // 8 MB
  unsigned short* xb    = (unsigned short*)(ws + (8ull << 20));      // 4 MB
  unsigned short* W1b   = (unsigned short*)(ws + (12ull << 20));     // 1 MB
  unsigned short* Wob   = (unsigned short*)(ws + (13ull << 20));     // 0.5 MB
  unsigned short* Vt    = (unsigned short*)(ws + (14ull << 20));     // 4 MB
  unsigned short* attnb = (unsigned short*)(ws + (18ull << 20));     // 4 MB
  unsigned char*  Mpack = ws + (38ull << 20) + (256u << 10);         // 512 KB

  prep<<<3968, 256, 0, stream>>>(x, in_proj_w, out_w, Mmask, V,
                                 xb, W1b, Wob, Mpack, Vt);
  gemm_qk<<<dim3(16, 32), 256, 0, stream>>>(xb, W1b, in_proj_b, qkb);
  flash_attn_fused<<<512, 512, 0, stream>>>(qkb, Vt, Mpack, attnb);
  gemm_out<<<dim3(8, 64), 256, 0, stream>>>(attnb, Wob, out_b, out);
}

// Round 11
// 131.022 us; speedup vs baseline: 1.1505x; 1.0074x over previous
//
#include <hip/hip_runtime.h>
#include <hip/hip_bf16.h>

// Problem constants (B=4, S=1024, d=512, H=8, hd=64)
#define BB 4
#define SS 1024
#define DD 512
#define HH 8
#define HD 64

typedef __attribute__((ext_vector_type(8))) short bf16x8;
typedef __attribute__((ext_vector_type(4))) float f32x4;

// fp32 -> bf16 round-to-nearest-even (finite inputs)
static __device__ __forceinline__ unsigned short f2b(float f) {
  union { float f; unsigned int u; } c; c.f = f;
  return (unsigned short)((c.u + 0x7fffu + ((c.u >> 16) & 1u)) >> 16);
}

// two fp32 -> packed bf16x2 (RNE, bit-identical to f2b pair) in ONE VALU op
static __device__ __forceinline__ unsigned cvtpk(float lo, float hi) {
  unsigned r;
  asm("v_cvt_pk_bf16_f32 %0, %1, %2" : "=v"(r) : "v"(lo), "v"(hi));
  return r;
}

// ---------------------------------------------------------------------------
// Fused prep (one dispatch, 3968 blocks):
//  [0,1024):    x fp32 -> bf16 (2M)
//  [1024,1280): in_proj_w q|k rows -> bf16 (512K)
//  [1280,1408): out_w -> bf16 (256K)
//  [1408,3456): mask bit-pack: 8 fp32 -> 1 byte
//  [3456,3968): V [B,S,H,hd] fp32 -> Vt [B,H,hd,S] bf16
// ---------------------------------------------------------------------------
__global__ __launch_bounds__(256) void prep(
    const float* __restrict__ x, const float* __restrict__ W1,
    const float* __restrict__ Wo, const float* __restrict__ Mmask,
    const float* __restrict__ V, unsigned short* __restrict__ xb,
    unsigned short* __restrict__ W1b, unsigned short* __restrict__ Wob,
    unsigned char* __restrict__ Mpack, unsigned short* __restrict__ Vt) {
  __shared__ float Ls[64][65];
  const int bid = blockIdx.x;
  const int tid = threadIdx.x;

  if (bid < 1408) {
    const float* src; unsigned short* dst; size_t off;
    if (bid < 1024) { src = x;  dst = xb;  off = ((size_t)bid * 256 + tid) * 8; }
    else if (bid < 1280) { src = W1; dst = W1b; off = ((size_t)(bid - 1024) * 256 + tid) * 8; }
    else { src = Wo; dst = Wob; off = ((size_t)(bid - 1280) * 256 + tid) * 8; }
    const float4 a = *(const float4*)(src + off);
    const float4 b = *(const float4*)(src + off + 4);
    union { unsigned short s[8]; uint4 v; } o;
    o.s[0] = f2b(a.x); o.s[1] = f2b(a.y); o.s[2] = f2b(a.z); o.s[3] = f2b(a.w);
    o.s[4] = f2b(b.x); o.s[5] = f2b(b.y); o.s[6] = f2b(b.z); o.s[7] = f2b(b.w);
    *(uint4*)(dst + off) = o.v;
  } else if (bid < 3456) {
    const size_t g = (size_t)(bid - 1408) * 256 + tid;
    const float4 a = *(const float4*)(Mmask + g * 8);
    const float4 b = *(const float4*)(Mmask + g * 8 + 4);
    unsigned v = 0;
    v |= (a.x > 0.5f) ? 1u : 0u;   v |= (a.y > 0.5f) ? 2u : 0u;
    v |= (a.z > 0.5f) ? 4u : 0u;   v |= (a.w > 0.5f) ? 8u : 0u;
    v |= (b.x > 0.5f) ? 16u : 0u;  v |= (b.y > 0.5f) ? 32u : 0u;
    v |= (b.z > 0.5f) ? 64u : 0u;  v |= (b.w > 0.5f) ? 128u : 0u;
    Mpack[g] = (unsigned char)v;
  } else {
    const int id = bid - 3456;
    const int s0 = (id & 15) * 64, h = (id >> 4) & 7, b = id >> 7;
    {
      const int r = tid >> 2, cs = (tid & 3) * 16;
      const float* src = V + ((size_t)((b * SS + s0 + r) * HH) + h) * HD + cs;
#pragma unroll
      for (int j = 0; j < 4; j++) {
        const float4 v = *(const float4*)(src + j * 4);
        Ls[r][cs + j * 4 + 0] = v.x; Ls[r][cs + j * 4 + 1] = v.y;
        Ls[r][cs + j * 4 + 2] = v.z; Ls[r][cs + j * 4 + 3] = v.w;
      }
    }
    __syncthreads();
    {
      const int d = tid >> 2, ss = (tid & 3) * 16;
      union { unsigned short s[16]; uint4 v[2]; } o;
#pragma unroll
      for (int j = 0; j < 16; j++) o.s[j] = f2b(Ls[ss + j][d]);
      unsigned short* dst =
          Vt + ((size_t)((b * HH + h) * HD + d)) * SS + s0 + ss;
      *(uint4*)dst = o.v[0];
      *(uint4*)(dst + 8) = o.v[1];
    }
  }
}

// ---------------------------------------------------------------------------
// GEMM1: qkb[4096,1024](bf16) = xb(bf16) @ W1b(bf16)^T + bias  (unchanged)
// ---------------------------------------------------------------------------
__global__ __launch_bounds__(256) void gemm_qk(
    const unsigned short* __restrict__ xb, const unsigned short* __restrict__ W1b,
    const float* __restrict__ bias, unsigned short* __restrict__ qkb) {
  __shared__ unsigned short As[128][40];
  __shared__ unsigned short Bs[64][40];
  const int tid = threadIdx.x;
  const int lane = tid & 63, wave = tid >> 6;
  const int l16 = lane & 15, quad = lane >> 4;
  const int row0 = blockIdx.y * 128, col0 = blockIdx.x * 64;

  f32x4 acc[2][4];
#pragma unroll
  for (int i = 0; i < 2; i++)
#pragma unroll
    for (int j = 0; j < 4; j++) acc[i][j] = (f32x4){0.f, 0.f, 0.f, 0.f};

  const int ra = tid >> 1, csa = (tid & 1) * 16;
  const int rb = tid >> 2, csb = (tid & 3) * 8;
  const unsigned short* ap = xb + (size_t)(row0 + ra) * DD + csa;
  const unsigned short* bp = W1b + (size_t)(col0 + rb) * DD + csb;

  uint4 pa0 = *(const uint4*)ap, pa1 = *(const uint4*)(ap + 8);
  uint4 pb = *(const uint4*)bp;

  for (int k0 = 0; k0 < DD; k0 += 32) {
    __syncthreads();
    *(uint4*)&As[ra][csa] = pa0;
    *(uint4*)&As[ra][csa + 8] = pa1;
    *(uint4*)&Bs[rb][csb] = pb;
    __syncthreads();
    if (k0 + 32 < DD) {  // prefetch next slab; vmcnt waits land next iter
      pa0 = *(const uint4*)(ap + k0 + 32);
      pa1 = *(const uint4*)(ap + k0 + 40);
      pb = *(const uint4*)(bp + k0 + 32);
    }

    const bf16x8 a0 = *(const bf16x8*)&As[wave * 32 + l16][quad * 8];
    const bf16x8 a1 = *(const bf16x8*)&As[wave * 32 + 16 + l16][quad * 8];
#pragma unroll
    for (int nt = 0; nt < 4; nt++) {
      const bf16x8 bb = *(const bf16x8*)&Bs[nt * 16 + l16][quad * 8];
      acc[0][nt] = __builtin_amdgcn_mfma_f32_16x16x32_bf16(a0, bb, acc[0][nt], 0, 0, 0);
      acc[1][nt] = __builtin_amdgcn_mfma_f32_16x16x32_bf16(a1, bb, acc[1][nt], 0, 0, 0);
    }
  }

#pragma unroll
  for (int nt = 0; nt < 4; nt++) {
    const int col = col0 + nt * 16 + l16;
    const float bv = bias[col];
    const float scale = (col < DD) ? 0.125f : 1.0f;
#pragma unroll
    for (int mi = 0; mi < 2; mi++)
#pragma unroll
      for (int reg = 0; reg < 4; reg++) {
        const int row = row0 + wave * 32 + mi * 16 + quad * 4 + reg;
        qkb[(size_t)row * 1024 + col] = f2b((acc[mi][nt][reg] + bv) * scale);
      }
  }
}

// ---------------------------------------------------------------------------
// GEMM3: out[4096,512](fp32) = attnb(bf16) @ Wob(bf16)^T + out_b  (unchanged)
// ---------------------------------------------------------------------------
__global__ __launch_bounds__(256) void gemm_out(
    const unsigned short* __restrict__ Ab, const unsigned short* __restrict__ Wob,
    const float* __restrict__ bias, float* __restrict__ out) {
  __shared__ unsigned short As[64][40];
  __shared__ unsigned short Bs[64][40];
  const int tid = threadIdx.x;
  const int lane = tid & 63, wave = tid >> 6;
  const int l16 = lane & 15, quad = lane >> 4;
  const int row0 = blockIdx.y * 64, col0 = blockIdx.x * 64;

  f32x4 acc[4];
#pragma unroll
  for (int j = 0; j < 4; j++) acc[j] = (f32x4){0.f, 0.f, 0.f, 0.f};

  const int r = tid >> 2, cs = (tid & 3) * 8;
  const unsigned short* ap = Ab + (size_t)(row0 + r) * DD + cs;
  const unsigned short* bp = Wob + (size_t)(col0 + r) * DD + cs;

  uint4 pa = *(const uint4*)ap;
  uint4 pb = *(const uint4*)bp;

  for (int k0 = 0; k0 < DD; k0 += 32) {
    __syncthreads();
    *(uint4*)&As[r][cs] = pa;
    *(uint4*)&Bs[r][cs] = pb;
    __syncthreads();
    if (k0 + 32 < DD) {
      pa = *(const uint4*)(ap + k0 + 32);
      pb = *(const uint4*)(bp + k0 + 32);
    }

    const bf16x8 a0 = *(const bf16x8*)&As[wave * 16 + l16][quad * 8];
#pragma unroll
    for (int nt = 0; nt < 4; nt++) {
      const bf16x8 bb = *(const bf16x8*)&Bs[nt * 16 + l16][quad * 8];
      acc[nt] = __builtin_amdgcn_mfma_f32_16x16x32_bf16(a0, bb, acc[nt], 0, 0, 0);
    }
  }

#pragma unroll
  for (int nt = 0; nt < 4; nt++) {
    const int col = col0 + nt * 16 + l16;
    const float bv = bias[col];
#pragma unroll
    for (int reg = 0; reg < 4; reg++) {
      const int row = row0 + wave * 16 + quad * 4 + reg;
      out[(size_t)row * DD + col] = acc[nt][reg] + bv;
    }
  }
}

// ---------------------------------------------------------------------------
// Fused split-k flash attention (FINAL = r14, best verified 130.4us):
//  - 512 thr / 8 waves; waves 0-3 = k-tiles [0,8), waves 4-7 = [8,16).
//  - K/V both halves staged in LDS per iter (register-prefetch, 2 barriers).
//    [r9/r15 proved direct-global operand reads on the MFMA path lose;
//     LDS staging is load-bearing despite barrier cost.]
//  - P in wave-private LDS rows (QP aliased for sp=0, P2 for sp=1).
//  - v_cvt_pk_bf16_f32 P pack (r14: -2.3us, bit-identical RNE).
//  - XCD-aware flat grid decode (r13: -2.8us): all 16 q-tiles of a (b,h)
//    group land on one XCD -> K/V slab L2-local.
//  - In-block split-k epilogue through LDS (r8: replaced Opart+combine
//    dispatch, -16MB fp32 partial round-trip).
//  - q pre-scaled 0.125 in gemm_qk -> exp(a) directly; no max shift,
//    no eps*Z term (rel ~2e-8).
// Not pursued (measured dead ends): setprio (r16 neutral), single-barrier
// V-direct (r15 +20us), 32x32 in-reg P (r11/r12 spill), 4-wave reuse (r10
// occupancy loss). Remaining headroom (~6-9us) would need the 8-phase
// counted-vmcnt template — race-risk not worth it at this noise floor.
// ---------------------------------------------------------------------------
__global__ __launch_bounds__(512, 4) void flash_attn_fused(
    const unsigned short* __restrict__ qkb, const unsigned short* __restrict__ Vt,
    const unsigned char* __restrict__ Mpack, unsigned short* __restrict__ attnb) {
  __shared__ unsigned short QP[64][72];     // Q staging; then P for sp=0 waves
  __shared__ unsigned short P2[64][72];     // P for sp=1 waves
  __shared__ unsigned short Ks[2][64][72];  // K tiles, both halves; epilogue O
  __shared__ unsigned short Vs[2][64][72];  // [d][s], both halves
  __shared__ float SmS[2][64];              // per-half row denominators

  const int tid = threadIdx.x;
  const int lane = tid & 63, wave = tid >> 6;
  const int l16 = lane & 15, quad = lane >> 4;
  const int wq = wave & 3, sp = wave >> 2;

  // XCD-aware decode: g%8 selects the XCD (round-robin dispatch); keep all
  // 16 q-tiles of a (b,h) group on one XCD. Bijective for 512 blocks.
  const int g = blockIdx.x;
  const int xcd = g & 7, loc = g >> 3;       // loc in [0,64)
  const int gr = xcd + 8 * (loc >> 4);       // (b,h) group in [0,32)
  const int q0 = (loc & 15) * 64;
  const int h = gr & 7;
  const int b = gr >> 3;

  const int r2 = tid >> 3, cs2 = (tid & 7) * 8;  // 512-thread staging

  {  // stage Q tile (all 64 rows; frags read into regs before P aliases it)
    const unsigned short* s = qkb + (size_t)(b * SS + q0 + r2) * 1024 + h * HD + cs2;
    *(uint4*)&QP[r2][cs2] = *(const uint4*)s;
  }

  // mask word pipeline: q = q0 + wq*16 + l16, this half's 8 k-tiles
  const unsigned char* mp =
      Mpack + (size_t)(b * SS + q0 + wq * 16 + l16) * 128 + sp * 64;
  uint2 pm = *(const uint2*)mp;

  __syncthreads();
  const bf16x8 bQ0 = *(const bf16x8*)&QP[wq * 16 + l16][quad * 8];
  const bf16x8 bQ1 = *(const bf16x8*)&QP[wq * 16 + l16][32 + quad * 8];
  unsigned short(*Ps)[72] =
      (unsigned short(*)[72])(sp ? &P2[wq * 16][0] : &QP[wq * 16][0]);

  float Smp = 0.f;
  f32x4 O[4];
#pragma unroll
  for (int i = 0; i < 4; i++) O[i] = (f32x4){0.f, 0.f, 0.f, 0.f};

  // per-thread staging pointers: each thread stages 16 B of K and V per half
  const unsigned short* kp0 =
      qkb + (size_t)(b * SS + r2) * 1024 + DD + h * HD + cs2;          // keys [0,512)
  const unsigned short* kp1 = kp0 + (size_t)512 * 1024;                 // keys [512,1024)
  const unsigned short* vp0 =
      Vt + ((size_t)((b * HH + h) * HD + r2)) * SS + cs2;
  const unsigned short* vp1 = vp0 + 512;

  uint4 pk0 = *(const uint4*)kp0, pk1 = *(const uint4*)kp1;
  uint4 pv0 = *(const uint4*)vp0, pv1 = *(const uint4*)vp1;

#pragma unroll
  for (int i = 0; i < 8; i++) {
    __syncthreads();  // prior iter's Ks/Vs frag reads complete
    *(uint4*)&Ks[0][r2][cs2] = pk0;
    *(uint4*)&Ks[1][r2][cs2] = pk1;
    *(uint4*)&Vs[0][r2][cs2] = pv0;
    *(uint4*)&Vs[1][r2][cs2] = pv1;
    __syncthreads();

    const uint2 pm_cur = pm;
    if (i < 7) {  // prefetch tile i+1; latency hidden by compute below
      pk0 = *(const uint4*)(kp0 + (size_t)(i + 1) * 64 * 1024);
      pk1 = *(const uint4*)(kp1 + (size_t)(i + 1) * 64 * 1024);
      pv0 = *(const uint4*)(vp0 + (i + 1) * 64);
      pv1 = *(const uint4*)(vp1 + (i + 1) * 64);
      pm = *(const uint2*)(mp + (i + 1) * 8);
    }

    // ---- S^T tiles: D[s=quad*4+reg][q=l16]; exp, mask-bit select, P pack ----
#pragma unroll
    for (int t = 0; t < 4; t++) {
      const bf16x8 aK0 = *(const bf16x8*)&Ks[sp][t * 16 + l16][quad * 8];
      const bf16x8 aK1 = *(const bf16x8*)&Ks[sp][t * 16 + l16][32 + quad * 8];
      f32x4 a = (f32x4){0.f, 0.f, 0.f, 0.f};
      a = __builtin_amdgcn_mfma_f32_16x16x32_bf16(aK0, bQ0, a, 0, 0, 0);
      a = __builtin_amdgcn_mfma_f32_16x16x32_bf16(aK1, bQ1, a, 0, 0, 0);
      const unsigned nib =
          ((t < 2 ? pm_cur.x : pm_cur.y) >> ((t & 1) * 16 + quad * 4)) & 0xFu;
      float e0 = __expf(a[0]); e0 = (nib & 1u) ? e0 : 0.f;
      float e1 = __expf(a[1]); e1 = (nib & 2u) ? e1 : 0.f;
      float e2 = __expf(a[2]); e2 = (nib & 4u) ? e2 : 0.f;
      float e3 = __expf(a[3]); e3 = (nib & 8u) ? e3 : 0.f;
      Smp += (e0 + e1) + (e2 + e3);
      uint2 w;
      w.x = cvtpk(e0, e1);   // v_cvt_pk_bf16_f32: 2 f32 -> bf16x2, RNE
      w.y = cvtpk(e2, e3);
      *(uint2*)&Ps[l16][t * 16 + quad * 4] = w;  // ds_write_b64, wave-private
    }

    // ---- O += P @ V (wave-private P; in-wave DS ordering suffices) ----
    const bf16x8 aP0 = *(const bf16x8*)&Ps[l16][quad * 8];
    const bf16x8 aP1 = *(const bf16x8*)&Ps[l16][32 + quad * 8];
#pragma unroll
    for (int dt = 0; dt < 4; dt++) {
      const bf16x8 bV0 = *(const bf16x8*)&Vs[sp][dt * 16 + l16][quad * 8];
      const bf16x8 bV1 = *(const bf16x8*)&Vs[sp][dt * 16 + l16][32 + quad * 8];
      O[dt] = __builtin_amdgcn_mfma_f32_16x16x32_bf16(aP0, bV0, O[dt], 0, 0, 0);
      O[dt] = __builtin_amdgcn_mfma_f32_16x16x32_bf16(aP1, bV1, O[dt], 0, 0, 0);
    }
  }

  // ---- epilogue: in-block split-k combine through LDS ----
  Smp += __shfl_xor(Smp, 16);
  Smp += __shfl_xor(Smp, 32);
  if (lane < 16) SmS[sp][wq * 16 + lane] = Smp;

  __syncthreads();  // all Ks reads drained; SmS visible
  float* Of = reinterpret_cast<float*>(&Ks[0][0][0]);  // 16 KB <= sizeof(Ks)
  if (sp == 1) {
#pragma unroll
    for (int dt = 0; dt < 4; dt++)
#pragma unroll
      for (int reg = 0; reg < 4; reg++)
        Of[(wq * 16 + quad * 4 + reg) * 64 + dt * 16 + l16] = O[dt][reg];
  }
  __syncthreads();

  if (sp == 0) {
    float inv[4];
#pragma unroll
    for (int reg = 0; reg < 4; reg++) {
      const int ql = wq * 16 + quad * 4 + reg;
      inv[reg] = 1.0f / (SmS[0][ql] + SmS[1][ql] + 1e-12f);
    }
#pragma unroll
    for (int dt = 0; dt < 4; dt++)
#pragma unroll
      for (int reg = 0; reg < 4; reg++) {
        const int ql = wq * 16 + quad * 4 + reg;
        const float v = (O[dt][reg] + Of[ql * 64 + dt * 16 + l16]) * inv[reg];
        attnb[(size_t)(b * SS + q0 + ql) * DD + h * HD + dt * 16 + l16] = f2b(v);
      }
  }
}

// ---------------------------------------------------------------------------
extern "C" void kernel_launch(void* const* d_in, const int* in_sizes, int n_in,
                              void* d_out, int out_size, void* d_ws,
                              size_t ws_size, hipStream_t stream) {
  const float* x = (const float*)d_in[0];          // [4,1024,512]
  const float* V = (const float*)d_in[1];          // [4,1024,8,64]
  const float* Mmask = (const float*)d_in[2];      // [4,1024,1024]
  const float* in_proj_w = (const float*)d_in[3];  // [1536,512]
  const float* in_proj_b = (const float*)d_in[4];  // [1536]
  const float* out_w = (const float*)d_in[5];      // [512,512]
  const float* out_b = (const float*)d_in[6];      // [512]
  float* out = (float*)d_out;                      // [4,1024,512]

  unsigned char* ws = (unsigned char*)d_ws;
  unsigned short* qkb   = (unsigned short*)(ws);                     // 8 MB
  unsigned short* xb    = (unsigned short*)(ws + (8ull << 20));      // 4 MB
  unsigned short* W1b   = (unsigned short*)(ws + (12ull << 20));     // 1 MB
  unsigned short* Wob   = (unsigned short*)(ws + (13ull << 20));     // 0.5 MB
  unsigned short* Vt    = (unsigned short*)(ws + (14ull << 20));     // 4 MB
  unsigned short* attnb = (unsigned short*)(ws + (18ull << 20));     // 4 MB
  unsigned char*  Mpack = ws + (38ull << 20) + (256u << 10);         // 512 KB

  prep<<<3968, 256, 0, stream>>>(x, in_proj_w, out_w, Mmask, V,
                                 xb, W1b, Wob, Mpack, Vt);
  gemm_qk<<<dim3(16, 32), 256, 0, stream>>>(xb, W1b, in_proj_b, qkb);
  flash_attn_fused<<<512, 512, 0, stream>>>(qkb, Vt, Mpack, attnb);
  gemm_out<<<dim3(8, 64), 256, 0, stream>>>(attnb, Wob, out_b, out);
}